// Round 3
// baseline (436.911 us; speedup 1.0000x reference)
//
#include <hip/hip_runtime.h>
#include <math.h>

#define BN 8192
#define ENC 256
#define NCL 32
#define TM 128

typedef __attribute__((ext_vector_type(8))) short short8;   // bf16x8 fragment
typedef __attribute__((ext_vector_type(4))) float f32x4;

__device__ __forceinline__ ushort f2bf(float x) {           // RNE float->bf16
    unsigned b = __float_as_uint(x);
    return (ushort)((b + 0x7FFFu + ((b >> 16) & 1u)) >> 16);
}

__device__ __forceinline__ void async16(void* lds, const void* g) {
    __builtin_amdgcn_global_load_lds(
        (const __attribute__((address_space(1))) unsigned*)g,
        (__attribute__((address_space(3))) unsigned*)lds, 16, 0, 0);
}

// ---------------- K1: sumsq + cat argmax + bf16 hi/lo split (granule-swizzled) ----------
// Swizzle: within each 64-elem K-step, 16B granule g -> g ^ (row&7). Linear
// global_load_lds then lands the XOR-swizzled layout in LDS (rule #21: swizzle
// the SOURCE, read with the same XOR).
__global__ void prep_kernel(const float* __restrict__ enc, const float* __restrict__ cat,
                            float* __restrict__ sq, float* __restrict__ maxg,
                            int* __restrict__ hard, ushort* __restrict__ eh,
                            ushort* __restrict__ el) {
    int w = threadIdx.x >> 6, l = threadIdx.x & 63;
    int row = blockIdx.x * 4 + w;
    const float4* e4 = (const float4*)(enc + (size_t)row * ENC);
    float4 v = e4[l];  // elements 4l..4l+3
    float s = v.x * v.x + v.y * v.y + v.z * v.z + v.w * v.w;
    for (int m = 32; m; m >>= 1) s += __shfl_xor(s, m, 64);

    ushort4 hh, ll;
    hh.x = f2bf(v.x); ll.x = f2bf(v.x - __uint_as_float((unsigned)hh.x << 16));
    hh.y = f2bf(v.y); ll.y = f2bf(v.y - __uint_as_float((unsigned)hh.y << 16));
    hh.z = f2bf(v.z); ll.z = f2bf(v.z - __uint_as_float((unsigned)hh.z << 16));
    hh.w = f2bf(v.w); ll.w = f2bf(v.w - __uint_as_float((unsigned)hh.w << 16));
    int g = l >> 1;                                   // original 16B granule 0..31
    int gs = (g & 24) | ((g & 7) ^ (row & 7));        // swizzled granule
    int kp = gs * 8 + (l & 1) * 4;                    // element offset in row
    *(ushort4*)(eh + (size_t)row * ENC + kp) = hh;
    *(ushort4*)(el + (size_t)row * ENC + kp) = ll;

    float cv = (l < NCL) ? cat[(size_t)row * NCL + l] : -__builtin_huge_valf();
    int ci = (l < NCL) ? l : 0x7fffffff;
    for (int m = 32; m; m >>= 1) {
        float ov = __shfl_xor(cv, m, 64);
        int oi = __shfl_xor(ci, m, 64);
        if (ov > cv || (ov == cv && oi < ci)) { cv = ov; ci = oi; }
    }
    if (l == 0) { sq[row] = s; maxg[row] = cv; hard[row] = ci; }
}

// ---------------- K2: split-bf16 MFMA distance GEMM (stores clamped d2) --------------
// dot = hi.hi + hi.lo + lo.hi (lo.lo dropped, ~2^-18 rel). 128x128 tile, BK=64,
// 4 waves (2x2), each wave 64x64 via 4x4 frags of 16x16x32 bf16 MFMA.
// No sqrt: selection and strict-< mask are monotone-invariant; clamp keeps d2>=0
// so uint ordering == float ordering downstream.
__global__ __launch_bounds__(256, 2)
void dist_mfma_kernel(const ushort* __restrict__ eh, const ushort* __restrict__ el,
                      const float* __restrict__ sq, float* __restrict__ dist, int row0) {
    __shared__ __align__(16) ushort lds[4 * TM * 64];  // 64 KB: Ah Al Bh Bl
    ushort* Ah = lds;
    ushort* Al = lds + TM * 64;
    ushort* Bh = lds + 2 * TM * 64;
    ushort* Bl = lds + 3 * TM * 64;

    int t = threadIdx.x, w = t >> 6, l = t & 63;
    int wm = w >> 1, wn = w & 1;
    int li0 = blockIdx.y * TM;         // chunk-local A rows (dist)
    int gi0 = row0 + li0;              // global A rows
    int j0 = blockIdx.x * TM;          // global B rows / dist cols

    f32x4 acc[4][4];
#pragma unroll
    for (int m = 0; m < 4; ++m)
#pragma unroll
        for (int n = 0; n < 4; ++n) acc[m][n] = (f32x4){0.f, 0.f, 0.f, 0.f};

    int srow = w * 32 + (l >> 3);      // staging row (+ q*8), wave covers 32 rows
    int selem = (l & 7) * 8;           // granule elem offset within K-step slice

    for (int k0 = 0; k0 < ENC; k0 += 64) {
        __syncthreads();               // LDS reads of previous step done
#pragma unroll
        for (int q = 0; q < 4; ++q) {
            int r = srow + q * 8;
            size_t ga = (size_t)(gi0 + r) * ENC + k0 + selem;
            size_t gb = (size_t)(j0 + r) * ENC + k0 + selem;
            int ldo = (w * 4 + q) * 512;  // ushort offset: 64 lanes x 16B
            async16(Ah + ldo, eh + ga);
            async16(Al + ldo, el + ga);
            async16(Bh + ldo, eh + gb);
            async16(Bl + ldo, el + gb);
        }
        __syncthreads();               // drains vmcnt (compiler) -> tiles ready

#pragma unroll
        for (int h = 0; h < 2; ++h) {  // two K=32 halves of the K-step
            short8 ah[4], al4[4], bh[4], bl4[4];
#pragma unroll
            for (int m = 0; m < 4; ++m) {
                int R = wm * 64 + m * 16 + (l & 15);
                int gq = (h * 4 + (l >> 4)) ^ (R & 7);   // un-swizzle on read
                ah[m]  = *(const short8*)(Ah + R * 64 + gq * 8);
                al4[m] = *(const short8*)(Al + R * 64 + gq * 8);
            }
#pragma unroll
            for (int n = 0; n < 4; ++n) {
                int R = wn * 64 + n * 16 + (l & 15);
                int gq = (h * 4 + (l >> 4)) ^ (R & 7);
                bh[n]  = *(const short8*)(Bh + R * 64 + gq * 8);
                bl4[n] = *(const short8*)(Bl + R * 64 + gq * 8);
            }
#pragma unroll
            for (int m = 0; m < 4; ++m)
#pragma unroll
                for (int n = 0; n < 4; ++n) {
                    acc[m][n] = __builtin_amdgcn_mfma_f32_16x16x32_bf16(ah[m],  bh[n],  acc[m][n], 0, 0, 0);
                    acc[m][n] = __builtin_amdgcn_mfma_f32_16x16x32_bf16(ah[m],  bl4[n], acc[m][n], 0, 0, 0);
                    acc[m][n] = __builtin_amdgcn_mfma_f32_16x16x32_bf16(al4[m], bh[n],  acc[m][n], 0, 0, 0);
                }
        }
    }

    // epilogue: C/D layout col=lane&15, row=(lane>>4)*4+reg (m89-verified)
    float sqi[16], sqj[4];
#pragma unroll
    for (int m = 0; m < 4; ++m)
#pragma unroll
        for (int r = 0; r < 4; ++r)
            sqi[m * 4 + r] = sq[gi0 + wm * 64 + m * 16 + (l >> 4) * 4 + r];
#pragma unroll
    for (int n = 0; n < 4; ++n) sqj[n] = sq[j0 + wn * 64 + n * 16 + (l & 15)];

#pragma unroll
    for (int m = 0; m < 4; ++m)
#pragma unroll
        for (int n = 0; n < 4; ++n)
#pragma unroll
            for (int r = 0; r < 4; ++r) {
                float d2 = sqi[m * 4 + r] + sqj[n] - 2.f * acc[m][n][r];
                size_t off = (size_t)(li0 + wm * 64 + m * 16 + (l >> 4) * 4 + r) * BN
                           + (size_t)(j0 + wn * 64 + n * 16 + (l & 15));
                dist[off] = fmaxf(d2, 0.f);   // clamped d2, no sqrt
            }
}

// ---------------- K3: barrier-free rank-26 select on d2, one wave per row ------------
__global__ __launch_bounds__(256, 2)
void select_kernel(const float* __restrict__ dist, const float* __restrict__ maxg,
                   const int* __restrict__ hard, const int* __restrict__ kptr,
                   float* __restrict__ out, int row0) {
    __shared__ int sbins[4 * NCL];
    int t = threadIdx.x, w = t >> 6, l = t & 63;
    int li = blockIdx.x * 4 + w;       // chunk-local row, one wave per row
    if (l < NCL) sbins[w * NCL + l] = 0;   // own wave's bins only: no barrier

    unsigned u[128];
    const float4* rd = (const float4*)(dist + (size_t)li * BN);
#pragma unroll
    for (int e = 0; e < 32; ++e) {
        float4 v = rd[e * 64 + l];
        u[e * 4 + 0] = __float_as_uint(v.x);
        u[e * 4 + 1] = __float_as_uint(v.y);
        u[e * 4 + 2] = __float_as_uint(v.z);
        u[e * 4 + 3] = __float_as_uint(v.w);
    }
    // Pin the working set in VGPRs: opaque asm defeats load rematerialization /
    // sinking into the search loop (last round: VGPR=72, search re-read via L2,
    // ~200 us). ~150 VGPRs fits the (256,2) cap of 256, no spill.
#pragma unroll
    for (int e = 0; e < 128; ++e) asm volatile("" : "+v"(u[e]));

    // row max -> search upper bound (d2 >= 0: uint order == float order)
    unsigned mx = u[0];
#pragma unroll
    for (int e = 1; e < 128; ++e) mx = u[e] > mx ? u[e] : mx;
    for (int m = 32; m; m >>= 1) {
        unsigned ox = (unsigned)__shfl_xor((int)mx, m, 64);
        mx = ox > mx ? ox : mx;
    }

    int topn = *kptr + 1;  // 26: thr = sorted[k]
    unsigned lo = 0u, hi = mx;
    while (lo < hi) {      // lo/hi wave-uniform (SGPR) -> scalar branch
        unsigned mid = lo + ((hi - lo) >> 1);
        int cnt = 0;
#pragma unroll
        for (int e = 0; e < 128; ++e)
            cnt += __popcll(__ballot(u[e] <= mid));  // v_cmp + SALU bcnt/add
        if (cnt >= topn) hi = mid; else lo = mid + 1;
    }
    unsigned thrb = lo;    // bit pattern of sorted[25] (in d2 domain)

#pragma unroll
    for (int e = 0; e < 32; ++e)
#pragma unroll
        for (int c = 0; c < 4; ++c)
            if (u[e * 4 + c] < thrb)
                atomicAdd(&sbins[w * NCL + hard[e * 256 + l * 4 + c]], 1);
    __syncthreads();       // cheap safety; bins are wave-local

    if (l < NCL) {
        int cnt = sbins[w * NCL + l];
        int n = cnt;
        for (int m = 16; m; m >>= 1) n += __shfl_xor(n, m, 64);
        float nf = (float)n;
        float b = (float)cnt / nf;
        float term = -b * logf(b + 1e-5f);
        for (int m = 16; m; m >>= 1) term += __shfl_xor(term, m, 64);
        if (l == 0) out[row0 + li] = term * maxg[row0 + li];
    }
}

extern "C" void kernel_launch(void* const* d_in, const int* in_sizes, int n_in,
                              void* d_out, int out_size, void* d_ws, size_t ws_size,
                              hipStream_t stream) {
    const float* enc = (const float*)d_in[0];
    const float* cat = (const float*)d_in[1];
    const int* kptr = (const int*)d_in[2];
    float* out = (float*)d_out;

    float* sq = (float*)d_ws;
    float* maxg = sq + BN;
    int* hard = (int*)(maxg + BN);
    ushort* eh = (ushort*)(hard + BN);
    ushort* el = eh + (size_t)BN * ENC;
    float* dist = (float*)(el + (size_t)BN * ENC);

    size_t head = (size_t)((char*)dist - (char*)d_ws);
    size_t avail = ws_size > head ? ws_size - head : 0;
    long max_rows = (long)(avail / ((size_t)BN * sizeof(float)));
    int chunk = (int)((max_rows / TM) * TM);
    if (chunk > BN) chunk = BN;
    if (chunk < TM) chunk = TM;

    prep_kernel<<<BN / 4, 256, 0, stream>>>(enc, cat, sq, maxg, hard, eh, el);

    for (int row0 = 0; row0 < BN; row0 += chunk) {
        int rows = BN - row0 < chunk ? BN - row0 : chunk;
        dim3 g(BN / TM, rows / TM);
        dist_mfma_kernel<<<g, 256, 0, stream>>>(eh, el, sq, dist, row0);
        select_kernel<<<rows / 4, 256, 0, stream>>>(dist, maxg, hard, kptr, out, row0);
    }
}

// Round 4
// 428.185 us; speedup vs baseline: 1.0204x; 1.0204x over previous
//
#include <hip/hip_runtime.h>
#include <math.h>

#define BN 8192
#define ENC 256
#define NCL 32
#define TM 128
#define HB 256   // radix histogram bins per pass

typedef __attribute__((ext_vector_type(8))) short short8;   // bf16x8 fragment
typedef __attribute__((ext_vector_type(4))) float f32x4;

__device__ __forceinline__ ushort f2bf(float x) {           // RNE float->bf16
    unsigned b = __float_as_uint(x);
    return (ushort)((b + 0x7FFFu + ((b >> 16) & 1u)) >> 16);
}

__device__ __forceinline__ void async16(void* lds, const void* g) {
    __builtin_amdgcn_global_load_lds(
        (const __attribute__((address_space(1))) unsigned*)g,
        (__attribute__((address_space(3))) unsigned*)lds, 16, 0, 0);
}

// ---------------- K1: sumsq + cat argmax + bf16 hi/lo split (granule-swizzled) ----------
__global__ void prep_kernel(const float* __restrict__ enc, const float* __restrict__ cat,
                            float* __restrict__ sq, float* __restrict__ maxg,
                            int* __restrict__ hard, ushort* __restrict__ eh,
                            ushort* __restrict__ el) {
    int w = threadIdx.x >> 6, l = threadIdx.x & 63;
    int row = blockIdx.x * 4 + w;
    const float4* e4 = (const float4*)(enc + (size_t)row * ENC);
    float4 v = e4[l];  // elements 4l..4l+3
    float s = v.x * v.x + v.y * v.y + v.z * v.z + v.w * v.w;
    for (int m = 32; m; m >>= 1) s += __shfl_xor(s, m, 64);

    ushort4 hh, ll;
    hh.x = f2bf(v.x); ll.x = f2bf(v.x - __uint_as_float((unsigned)hh.x << 16));
    hh.y = f2bf(v.y); ll.y = f2bf(v.y - __uint_as_float((unsigned)hh.y << 16));
    hh.z = f2bf(v.z); ll.z = f2bf(v.z - __uint_as_float((unsigned)hh.z << 16));
    hh.w = f2bf(v.w); ll.w = f2bf(v.w - __uint_as_float((unsigned)hh.w << 16));
    int g = l >> 1;                                   // original 16B granule 0..31
    int gs = (g & 24) | ((g & 7) ^ (row & 7));        // swizzled granule
    int kp = gs * 8 + (l & 1) * 4;                    // element offset in row
    *(ushort4*)(eh + (size_t)row * ENC + kp) = hh;
    *(ushort4*)(el + (size_t)row * ENC + kp) = ll;

    float cv = (l < NCL) ? cat[(size_t)row * NCL + l] : -__builtin_huge_valf();
    int ci = (l < NCL) ? l : 0x7fffffff;
    for (int m = 32; m; m >>= 1) {
        float ov = __shfl_xor(cv, m, 64);
        int oi = __shfl_xor(ci, m, 64);
        if (ov > cv || (ov == cv && oi < ci)) { cv = ov; ci = oi; }
    }
    if (l == 0) { sq[row] = s; maxg[row] = cv; hard[row] = ci; }
}

// ---------------- K2: split-bf16 MFMA distance GEMM (stores clamped d2) --------------
__global__ __launch_bounds__(256, 2)
void dist_mfma_kernel(const ushort* __restrict__ eh, const ushort* __restrict__ el,
                      const float* __restrict__ sq, float* __restrict__ dist, int row0) {
    __shared__ __align__(16) ushort lds[4 * TM * 64];  // 64 KB: Ah Al Bh Bl
    ushort* Ah = lds;
    ushort* Al = lds + TM * 64;
    ushort* Bh = lds + 2 * TM * 64;
    ushort* Bl = lds + 3 * TM * 64;

    int t = threadIdx.x, w = t >> 6, l = t & 63;
    int wm = w >> 1, wn = w & 1;
    int li0 = blockIdx.y * TM;         // chunk-local A rows (dist)
    int gi0 = row0 + li0;              // global A rows
    int j0 = blockIdx.x * TM;          // global B rows / dist cols

    f32x4 acc[4][4];
#pragma unroll
    for (int m = 0; m < 4; ++m)
#pragma unroll
        for (int n = 0; n < 4; ++n) acc[m][n] = (f32x4){0.f, 0.f, 0.f, 0.f};

    int srow = w * 32 + (l >> 3);      // staging row (+ q*8), wave covers 32 rows
    int selem = (l & 7) * 8;           // granule elem offset within K-step slice

    for (int k0 = 0; k0 < ENC; k0 += 64) {
        __syncthreads();               // LDS reads of previous step done
#pragma unroll
        for (int q = 0; q < 4; ++q) {
            int r = srow + q * 8;
            size_t ga = (size_t)(gi0 + r) * ENC + k0 + selem;
            size_t gb = (size_t)(j0 + r) * ENC + k0 + selem;
            int ldo = (w * 4 + q) * 512;  // ushort offset: 64 lanes x 16B
            async16(Ah + ldo, eh + ga);
            async16(Al + ldo, el + ga);
            async16(Bh + ldo, eh + gb);
            async16(Bl + ldo, el + gb);
        }
        __syncthreads();               // drains vmcnt (compiler) -> tiles ready

#pragma unroll
        for (int h = 0; h < 2; ++h) {  // two K=32 halves of the K-step
            short8 ah[4], al4[4], bh[4], bl4[4];
#pragma unroll
            for (int m = 0; m < 4; ++m) {
                int R = wm * 64 + m * 16 + (l & 15);
                int gq = (h * 4 + (l >> 4)) ^ (R & 7);   // un-swizzle on read
                ah[m]  = *(const short8*)(Ah + R * 64 + gq * 8);
                al4[m] = *(const short8*)(Al + R * 64 + gq * 8);
            }
#pragma unroll
            for (int n = 0; n < 4; ++n) {
                int R = wn * 64 + n * 16 + (l & 15);
                int gq = (h * 4 + (l >> 4)) ^ (R & 7);
                bh[n]  = *(const short8*)(Bh + R * 64 + gq * 8);
                bl4[n] = *(const short8*)(Bl + R * 64 + gq * 8);
            }
#pragma unroll
            for (int m = 0; m < 4; ++m)
#pragma unroll
                for (int n = 0; n < 4; ++n) {
                    acc[m][n] = __builtin_amdgcn_mfma_f32_16x16x32_bf16(ah[m],  bh[n],  acc[m][n], 0, 0, 0);
                    acc[m][n] = __builtin_amdgcn_mfma_f32_16x16x32_bf16(ah[m],  bl4[n], acc[m][n], 0, 0, 0);
                    acc[m][n] = __builtin_amdgcn_mfma_f32_16x16x32_bf16(al4[m], bh[n],  acc[m][n], 0, 0, 0);
                }
        }
    }

    // epilogue: C/D layout col=lane&15, row=(lane>>4)*4+reg (m89-verified)
    float sqi[16], sqj[4];
#pragma unroll
    for (int m = 0; m < 4; ++m)
#pragma unroll
        for (int r = 0; r < 4; ++r)
            sqi[m * 4 + r] = sq[gi0 + wm * 64 + m * 16 + (l >> 4) * 4 + r];
#pragma unroll
    for (int n = 0; n < 4; ++n) sqj[n] = sq[j0 + wn * 64 + n * 16 + (l & 15)];

#pragma unroll
    for (int m = 0; m < 4; ++m)
#pragma unroll
        for (int n = 0; n < 4; ++n)
#pragma unroll
            for (int r = 0; r < 4; ++r) {
                float d2 = sqi[m * 4 + r] + sqj[n] - 2.f * acc[m][n][r];
                size_t off = (size_t)(li0 + wm * 64 + m * 16 + (l >> 4) * 4 + r) * BN
                           + (size_t)(j0 + wn * 64 + n * 16 + (l & 15));
                dist[off] = fmaxf(d2, 0.f);   // clamped d2, no sqrt
            }
}

// ---------------- K3: LDS-staged exact radix select (rank topn) + entropy ------------
// One block per row. Row staged in LDS once; 4 radix passes (8/8/8/7 bits) over
// per-wave 256-bin histograms find the exact bit pattern of sorted[k]; final LDS
// scan does the strict-< mask + per-cluster counts. No big register arrays, so
// no remat/spill hazard (round-2/3 lesson).
__device__ __forceinline__ int block_pick(int s, int t, int w, int l,
                                          int* wpart, int* sbc) {
    int incl = s;
#pragma unroll
    for (int m = 1; m < 64; m <<= 1) {
        int o = __shfl_up(incl, m, 64);
        if (l >= m) incl += o;
    }
    if (l == 63) wpart[w] = incl;
    __syncthreads();                       // wpart visible (and prior hist reads done)
    int woff = 0;
#pragma unroll
    for (int i = 0; i < 4; ++i) woff += (i < w) ? wpart[i] : 0;
    incl += woff;
    int excl = incl - s;
    int rem = sbc[1];
    __syncthreads();                       // all read rem before winner overwrites
    if (excl < rem && rem <= incl) { sbc[0] = t; sbc[1] = rem - excl; }
    __syncthreads();
    return sbc[0];
}

__global__ __launch_bounds__(256, 4)
void select_kernel(const float* __restrict__ dist, const float* __restrict__ maxg,
                   const int* __restrict__ hard, const int* __restrict__ kptr,
                   float* __restrict__ out, int row0) {
    __shared__ __align__(16) float srow[BN];   // 32 KB staged d2 row
    __shared__ int hist[HB][4];                // skewed: 4 waves' hot bins on 4 banks
    __shared__ int sbins[NCL];
    __shared__ int wpart[4];
    __shared__ int sbc[2];                     // {picked bin, remaining rank}

    int t = threadIdx.x, w = t >> 6, l = t & 63;
    int li = blockIdx.x;                       // chunk-local row

    int* hf = (int*)hist;
    hf[t] = 0; hf[t + 256] = 0; hf[t + 512] = 0; hf[t + 768] = 0;
    if (t < NCL) sbins[t] = 0;
    if (t == 0) sbc[1] = *kptr + 1;            // topn = 26: thr = sorted[k]
    __syncthreads();

    // P1: global load -> LDS stage, fused with top-8-bit histogram (u>>23: sign=0)
    const float4* rg = (const float4*)(dist + (size_t)li * BN);
    float4* r4 = (float4*)srow;
#pragma unroll
    for (int r = 0; r < 8; ++r) {
        float4 v = rg[r * 256 + t];
        r4[r * 256 + t] = v;
        atomicAdd(&hist[__float_as_uint(v.x) >> 23][w], 1);
        atomicAdd(&hist[__float_as_uint(v.y) >> 23][w], 1);
        atomicAdd(&hist[__float_as_uint(v.z) >> 23][w], 1);
        atomicAdd(&hist[__float_as_uint(v.w) >> 23][w], 1);
    }
    __syncthreads();

    unsigned pfx = (unsigned)block_pick(
        hist[t][0] + hist[t][1] + hist[t][2] + hist[t][3], t, w, l, wpart, sbc);

    // P2: bits 22:15 among values matching pfx on bits 30:23
    hf[t] = 0; hf[t + 256] = 0; hf[t + 512] = 0; hf[t + 768] = 0;
    __syncthreads();
#pragma unroll
    for (int r = 0; r < 8; ++r) {
        float4 v = r4[r * 256 + t];
        unsigned a = __float_as_uint(v.x), b = __float_as_uint(v.y);
        unsigned c = __float_as_uint(v.z), d = __float_as_uint(v.w);
        if ((a >> 23) == pfx) atomicAdd(&hist[(a >> 15) & 255][w], 1);
        if ((b >> 23) == pfx) atomicAdd(&hist[(b >> 15) & 255][w], 1);
        if ((c >> 23) == pfx) atomicAdd(&hist[(c >> 15) & 255][w], 1);
        if ((d >> 23) == pfx) atomicAdd(&hist[(d >> 15) & 255][w], 1);
    }
    __syncthreads();
    pfx = (pfx << 8) | (unsigned)block_pick(
        hist[t][0] + hist[t][1] + hist[t][2] + hist[t][3], t, w, l, wpart, sbc);

    // P3: bits 14:7 among values matching pfx on bits 30:15
    hf[t] = 0; hf[t + 256] = 0; hf[t + 512] = 0; hf[t + 768] = 0;
    __syncthreads();
#pragma unroll
    for (int r = 0; r < 8; ++r) {
        float4 v = r4[r * 256 + t];
        unsigned a = __float_as_uint(v.x), b = __float_as_uint(v.y);
        unsigned c = __float_as_uint(v.z), d = __float_as_uint(v.w);
        if ((a >> 15) == pfx) atomicAdd(&hist[(a >> 7) & 255][w], 1);
        if ((b >> 15) == pfx) atomicAdd(&hist[(b >> 7) & 255][w], 1);
        if ((c >> 15) == pfx) atomicAdd(&hist[(c >> 7) & 255][w], 1);
        if ((d >> 15) == pfx) atomicAdd(&hist[(d >> 7) & 255][w], 1);
    }
    __syncthreads();
    pfx = (pfx << 8) | (unsigned)block_pick(
        hist[t][0] + hist[t][1] + hist[t][2] + hist[t][3], t, w, l, wpart, sbc);

    // P4: bits 6:0 among values matching pfx on bits 30:7
    hf[t] = 0; hf[t + 256] = 0; hf[t + 512] = 0; hf[t + 768] = 0;
    __syncthreads();
#pragma unroll
    for (int r = 0; r < 8; ++r) {
        float4 v = r4[r * 256 + t];
        unsigned a = __float_as_uint(v.x), b = __float_as_uint(v.y);
        unsigned c = __float_as_uint(v.z), d = __float_as_uint(v.w);
        if ((a >> 7) == pfx) atomicAdd(&hist[a & 127][w], 1);
        if ((b >> 7) == pfx) atomicAdd(&hist[b & 127][w], 1);
        if ((c >> 7) == pfx) atomicAdd(&hist[c & 127][w], 1);
        if ((d >> 7) == pfx) atomicAdd(&hist[d & 127][w], 1);
    }
    __syncthreads();
    unsigned thrb = (pfx << 7) | (unsigned)block_pick(
        hist[t][0] + hist[t][1] + hist[t][2] + hist[t][3], t, w, l, wpart, sbc);
    // thrb = exact bit pattern of sorted[k] in the d2 domain

    // Final: strict < thrb -> per-cluster counts (rare hits)
#pragma unroll
    for (int r = 0; r < 8; ++r) {
        float4 v = r4[r * 256 + t];
        int j = (r * 256 + t) * 4;
        if (__float_as_uint(v.x) < thrb) atomicAdd(&sbins[hard[j + 0]], 1);
        if (__float_as_uint(v.y) < thrb) atomicAdd(&sbins[hard[j + 1]], 1);
        if (__float_as_uint(v.z) < thrb) atomicAdd(&sbins[hard[j + 2]], 1);
        if (__float_as_uint(v.w) < thrb) atomicAdd(&sbins[hard[j + 3]], 1);
    }
    __syncthreads();

    // entropy epilogue: wave 0, lanes 0..31 = clusters
    if (t < NCL) {
        int cnt = sbins[t];
        int n = cnt;
        for (int m = 16; m; m >>= 1) n += __shfl_xor(n, m, 64);
        float nf = (float)n;
        float b = (float)cnt / nf;
        float term = -b * logf(b + 1e-5f);
        for (int m = 16; m; m >>= 1) term += __shfl_xor(term, m, 64);
        if (t == 0) out[row0 + li] = term * maxg[row0 + li];
    }
}

extern "C" void kernel_launch(void* const* d_in, const int* in_sizes, int n_in,
                              void* d_out, int out_size, void* d_ws, size_t ws_size,
                              hipStream_t stream) {
    const float* enc = (const float*)d_in[0];
    const float* cat = (const float*)d_in[1];
    const int* kptr = (const int*)d_in[2];
    float* out = (float*)d_out;

    float* sq = (float*)d_ws;
    float* maxg = sq + BN;
    int* hard = (int*)(maxg + BN);
    ushort* eh = (ushort*)(hard + BN);
    ushort* el = eh + (size_t)BN * ENC;
    float* dist = (float*)(el + (size_t)BN * ENC);

    size_t head = (size_t)((char*)dist - (char*)d_ws);
    size_t avail = ws_size > head ? ws_size - head : 0;
    long max_rows = (long)(avail / ((size_t)BN * sizeof(float)));
    int chunk = (int)((max_rows / TM) * TM);
    if (chunk > BN) chunk = BN;
    if (chunk < TM) chunk = TM;

    prep_kernel<<<BN / 4, 256, 0, stream>>>(enc, cat, sq, maxg, hard, eh, el);

    for (int row0 = 0; row0 < BN; row0 += chunk) {
        int rows = BN - row0 < chunk ? BN - row0 : chunk;
        dim3 g(BN / TM, rows / TM);
        dist_mfma_kernel<<<g, 256, 0, stream>>>(eh, el, sq, dist, row0);
        select_kernel<<<rows, 256, 0, stream>>>(dist, maxg, hard, kptr, out, row0);
    }
}